// Round 1
// baseline (1706.452 us; speedup 1.0000x reference)
//
#include <hip/hip_runtime.h>
#include <cstdint>
#include <cstddef>

// ---------------- problem constants ----------------
#define VOCAB  50257
#define VPAD   50304          // 393 * 128, zero-padded W rows
#define DIMK   768
#define MROWS  4096           // B*S = 2*2048
#define NBLK   393            // VPAD / 128
#define MBLK   32             // MROWS / 128
#define LSCALE 20.0f          // 1/eps

typedef __bf16 bf16x8 __attribute__((ext_vector_type(8)));
typedef float  floatx4 __attribute__((ext_vector_type(4)));

typedef const void __attribute__((address_space(1)))* gptr1_t;
typedef void __attribute__((address_space(3)))* lptr3_t;

__device__ __forceinline__ void async_copy16(const void* g, void* l) {
  // 16B/lane direct global->LDS; LDS dest is wave-uniform base + lane*16
  __builtin_amdgcn_global_load_lds((gptr1_t)g, (lptr3_t)l, 16, 0, 0);
}

__device__ __forceinline__ unsigned short f2bf(float f) {
  union { float f; unsigned u; } x; x.f = f;
  unsigned r = x.u + 0x7fffu + ((x.u >> 16) & 1u);   // RNE (finite inputs)
  return (unsigned short)(r >> 16);
}

// ---------------- stage 1: row L2-normalize, fp32 -> bf16 ----------------
// one block per row, 256 threads, D=768 -> 3 elems/thread.
// rows >= valid_rows are written as zeros (W padding).
__global__ void norm_rows_kernel(const float* __restrict__ in,
                                 unsigned short* __restrict__ outb,
                                 int valid_rows) {
  const int row = blockIdx.x;
  const int t = threadIdx.x;
  float v0 = 0.f, v1 = 0.f, v2 = 0.f;
  if (row < valid_rows) {
    const float* p = in + (size_t)row * DIMK;
    v0 = p[t]; v1 = p[t + 256]; v2 = p[t + 512];
  }
  float ss = v0 * v0 + v1 * v1 + v2 * v2;
#pragma unroll
  for (int off = 32; off > 0; off >>= 1) ss += __shfl_xor(ss, off);
  __shared__ float wss[4];
  if ((t & 63) == 0) wss[t >> 6] = ss;
  __syncthreads();
  const float tot = wss[0] + wss[1] + wss[2] + wss[3];
  const float sc = 1.0f / fmaxf(sqrtf(tot), 1e-12f);  // matches F.normalize
  unsigned short* q = outb + (size_t)row * DIMK;
  q[t]       = f2bf(v0 * sc);
  q[t + 256] = f2bf(v1 * sc);
  q[t + 512] = f2bf(v2 * sc);
}

// ---------------- stage 2: bf16 GEMM (m97 recipe) + exp-sum epilogue ------
// C[m,n] = sum_k A[m,k]*B[n,k]  (B stored row-major [N][K] == B^T GEMM)
// 128x128 tile, BK=32, 4 waves of 2x2 x (64x64 per wave), 16x16x32 MFMA.
__global__ __launch_bounds__(256)
void gemm_kernel(const unsigned short* __restrict__ A,   // [MROWS][K] bf16
                 const unsigned short* __restrict__ Bw,  // [VPAD][K] bf16
                 float* __restrict__ out,                // [MROWS][VOCAB]
                 float* __restrict__ row_sums) {         // [MROWS]
  __shared__ __align__(16) unsigned short As[128 * 32];
  __shared__ __align__(16) unsigned short Bs[128 * 32];
  const int tid  = threadIdx.x;
  const int wave = tid >> 6;
  const int lane = tid & 63;
  const int lhi  = lane >> 4;   // quad 0..3
  const int llo  = lane & 15;
  const int wm   = wave >> 1;   // wave row 0..1
  const int wn   = wave & 1;    // wave col 0..1
  const int rowBase = blockIdx.y * 128;
  const int colBase = blockIdx.x * 128;

  floatx4 acc[4][4];
#pragma unroll
  for (int i = 0; i < 4; ++i)
#pragma unroll
    for (int j = 0; j < 4; ++j)
      acc[i][j] = (floatx4){0.f, 0.f, 0.f, 0.f};

  // staging: 512 x 16B chunks per tile; chunk c -> row c>>2, kchunk c&3.
  // LDS layout [row][k] row-major (64B rows) => LDS byte off == c*16, which
  // matches HW's wave-uniform base + lane*16 ordering exactly.
  const int c0 = (wave * 2 + 0) * 64 + lane;
  const int c1 = (wave * 2 + 1) * 64 + lane;
  const unsigned short* Ag0 = A  + (size_t)(rowBase + (c0 >> 2)) * DIMK + (c0 & 3) * 8;
  const unsigned short* Ag1 = A  + (size_t)(rowBase + (c1 >> 2)) * DIMK + (c1 & 3) * 8;
  const unsigned short* Bg0 = Bw + (size_t)(colBase + (c0 >> 2)) * DIMK + (c0 & 3) * 8;
  const unsigned short* Bg1 = Bw + (size_t)(colBase + (c1 >> 2)) * DIMK + (c1 & 3) * 8;
  unsigned short* Al0 = As + (wave * 2 + 0) * 512;
  unsigned short* Al1 = As + (wave * 2 + 1) * 512;
  unsigned short* Bl0 = Bs + (wave * 2 + 0) * 512;
  unsigned short* Bl1 = Bs + (wave * 2 + 1) * 512;

  for (int k0 = 0; k0 < DIMK; k0 += 32) {
    __syncthreads();                 // prev tile's LDS reads complete
    async_copy16(Ag0 + k0, Al0);
    async_copy16(Ag1 + k0, Al1);
    async_copy16(Bg0 + k0, Bl0);
    async_copy16(Bg1 + k0, Bl1);
    __syncthreads();                 // staging drained (vmcnt(0) at barrier)

    bf16x8 af[4], bfr[4];
#pragma unroll
    for (int fr = 0; fr < 4; ++fr)
      af[fr] = *(const bf16x8*)&As[(wm * 64 + fr * 16 + llo) * 32 + lhi * 8];
#pragma unroll
    for (int fc = 0; fc < 4; ++fc)
      bfr[fc] = *(const bf16x8*)&Bs[(wn * 64 + fc * 16 + llo) * 32 + lhi * 8];
#pragma unroll
    for (int fr = 0; fr < 4; ++fr)
#pragma unroll
      for (int fc = 0; fc < 4; ++fc)
        acc[fr][fc] = __builtin_amdgcn_mfma_f32_16x16x32_bf16(
            af[fr], bfr[fc], acc[fr][fc], 0, 0, 0);
  }

  // epilogue: l = 20*cos; store; accumulate sum(exp(l-20)) per row.
  // C/D layout: col = lane&15, row = quad*4 + reg  (verified m89/m91)
  const int growBase = rowBase + wm * 64;
  const int gcolBase = colBase + wn * 64;
  float myrowsum = 0.f;
  int   myrow = growBase;
#pragma unroll
  for (int fr = 0; fr < 4; ++fr) {
#pragma unroll
    for (int r = 0; r < 4; ++r) {
      const int grow = growBase + fr * 16 + lhi * 4 + r;
      float s = 0.f;
#pragma unroll
      for (int fc = 0; fc < 4; ++fc) {
        const int gcol = gcolBase + fc * 16 + llo;
        const float l = acc[fr][fc][r] * LSCALE;
        if (gcol < VOCAB) {
          out[(size_t)grow * VOCAB + gcol] = l;
          s += __expf(l - LSCALE);   // fixed max = 20 (|l| <= 20)
        }
      }
      // reduce across the 16 lanes sharing this row (xor 1,2,4,8)
      s += __shfl_xor(s, 1);
      s += __shfl_xor(s, 2);
      s += __shfl_xor(s, 4);
      s += __shfl_xor(s, 8);
      if (llo == fr * 4 + r) { myrowsum = s; myrow = grow; }
    }
  }
  atomicAdd(&row_sums[myrow], myrowsum);  // one atomic per lane, 64/wave
}

// ---------------- stage 3: lse = 20 + log(sum) ----------------
__global__ void lse_fin_kernel(const float* __restrict__ sums,
                               float* __restrict__ lse) {
  const int i = blockIdx.x * 256 + threadIdx.x;
  if (i < MROWS) lse[i] = LSCALE + logf(sums[i]);
}

// ---------------- stage 4: out = l - lse[row] + bias[col] ----------------
#define TOT4 51463168u   // (4096*50257)/4
__global__ void apply_kernel(float* __restrict__ out,
                             const float* __restrict__ lse,
                             const float* __restrict__ bias) {
  const unsigned i = blockIdx.x * 256 + threadIdx.x;
  if (i >= TOT4) return;
  float4 v = reinterpret_cast<float4*>(out)[i];
  const unsigned b0 = i * 4u;
  unsigned idx, row, col;
  idx = b0 + 0u; row = idx / (unsigned)VOCAB; col = idx - row * (unsigned)VOCAB;
  v.x = v.x - lse[row] + bias[col];
  idx = b0 + 1u; row = idx / (unsigned)VOCAB; col = idx - row * (unsigned)VOCAB;
  v.y = v.y - lse[row] + bias[col];
  idx = b0 + 2u; row = idx / (unsigned)VOCAB; col = idx - row * (unsigned)VOCAB;
  v.z = v.z - lse[row] + bias[col];
  idx = b0 + 3u; row = idx / (unsigned)VOCAB; col = idx - row * (unsigned)VOCAB;
  v.w = v.w - lse[row] + bias[col];
  reinterpret_cast<float4*>(out)[i] = v;
}

// ---------------- launch ----------------
extern "C" void kernel_launch(void* const* d_in, const int* in_sizes, int n_in,
                              void* d_out, int out_size, void* d_ws, size_t ws_size,
                              hipStream_t stream) {
  const float* x    = (const float*)d_in[0];   // [2,2048,768]
  const float* w    = (const float*)d_in[1];   // [50257,768]
  const float* bias = (const float*)d_in[2];   // [50257]
  float* out = (float*)d_out;                  // [4096,50257]

  // workspace layout (ws re-poisoned each call -> re-init everything we need)
  unsigned short* xn = (unsigned short*)d_ws;              // 4096*768 bf16
  unsigned short* wn = xn + (size_t)MROWS * DIMK;          // 50304*768 bf16
  float* sums = (float*)(wn + (size_t)VPAD * DIMK);        // 4096 f32
  float* lse  = sums + MROWS;                              // 4096 f32

  hipMemsetAsync(sums, 0, MROWS * sizeof(float), stream);
  norm_rows_kernel<<<MROWS, 256, 0, stream>>>(x, xn, MROWS);
  norm_rows_kernel<<<VPAD, 256, 0, stream>>>(w, wn, VOCAB);
  dim3 g(NBLK, MBLK);
  gemm_kernel<<<g, 256, 0, stream>>>(xn, wn, out, sums);
  lse_fin_kernel<<<(MROWS + 255) / 256, 256, 0, stream>>>(sums, lse);
  apply_kernel<<<(TOT4 + 255u) / 256u, 256, 0, stream>>>(out, lse, bias);
}